// Round 1
// baseline (58.328 us; speedup 1.0000x reference)
//
#include <hip/hip_runtime.h>

// QuantumSelfAttention: closed-form collapse of the 10-qubit staircase circuit.
//
//   q_0 = cos(x_0 + r_0)
//   q_j = cos(x_j + r_j) * (1 + sp2_{j-1} * (q_{j-1} - 1)),  sp2_i = sin^2(ent_i/2)
//
// O(n) per sample instead of O(n*2^n). (Math unchanged from the harness-verified
// previous version; this round only restructures memory access.)
//
// This version: cooperative LDS staging so ALL global traffic is coalesced
// float4 (16 B/lane). Each 256-thread block owns 256 rows = 10240 B.
// Per-row access (40 B stride) happens in LDS where the 4-way bank aliasing
// costs ~nothing at this op count.

#define N_Q   10
#define ROWS  256                    // rows per block == threads per block
#define BLK_F (ROWS * N_Q)           // 2560 floats staged per block
#define BLK_V4 (BLK_F / 4)           // 640 float4 per block

__global__ __launch_bounds__(ROWS) void qsa_kernel(
    const float* __restrict__ x,     // (T, 10)
    const float* __restrict__ rot,   // (10,)
    const float* __restrict__ ent,   // (9,)
    float* __restrict__ out,         // (T, 10)
    int T)
{
    __shared__ float4 buf4[BLK_V4];          // 10240 B row buffer (in, then out)
    __shared__ float  s_r[N_Q];
    __shared__ float  s_sp2[N_Q - 1];

    float* buf = reinterpret_cast<float*>(buf4);
    const int tid       = threadIdx.x;
    const int row0      = blockIdx.x * ROWS; // first row this block owns
    const int total_v4  = (T * N_Q) / 4;     // global float4 count (T*10 is /4 for even T)
    const int base_v4   = (row0 * N_Q) / 4;  // this block's float4 offset (16B-aligned)

    // --- Stage 1: fully-coalesced float4 global -> LDS (640 float4 / block) ---
    const float4* src = reinterpret_cast<const float4*>(x) + base_v4;
#pragma unroll
    for (int k = 0; k < 3; ++k) {
        int idx = k * ROWS + tid;
        if (idx < BLK_V4 && base_v4 + idx < total_v4) buf4[idx] = src[idx];
    }

    // --- Params once per block (uniform-address loads + 9 sinf total) ---
    if (tid < N_Q)     s_r[tid] = rot[tid];
    if (tid < N_Q - 1) {
        float s = __sinf(0.5f * ent[tid]);
        s_sp2[tid] = s * s;
    }
    __syncthreads();

    const int my_row = row0 + tid;
    if (my_row < T) {
        // --- Per-thread row from LDS (exclusive ownership; no cross-thread hazard) ---
        float* row = buf + tid * N_Q;
        float xv[N_Q];
#pragma unroll
        for (int j = 0; j < N_Q; ++j) xv[j] = row[j];

        // --- Markov recursion for <Z_j> ---
        float o[N_Q];
        float q = __cosf(xv[0] + s_r[0]);
        o[0] = q;
#pragma unroll
        for (int j = 1; j < N_Q; ++j) {
            float d = __cosf(xv[j] + s_r[j]);
            // q = d * ((1 - sp2) + sp2 * q) = d * (1 + sp2*(q-1))
            q = d * fmaf(s_sp2[j - 1], q - 1.0f, 1.0f);
            o[j] = q;
        }

        // --- Write result back into the same LDS row ---
#pragma unroll
        for (int j = 0; j < N_Q; ++j) row[j] = o[j];
    }
    __syncthreads();

    // --- Stage 2: fully-coalesced float4 LDS -> global ---
    float4* dst = reinterpret_cast<float4*>(out) + base_v4;
#pragma unroll
    for (int k = 0; k < 3; ++k) {
        int idx = k * ROWS + tid;
        if (idx < BLK_V4 && base_v4 + idx < total_v4) dst[idx] = buf4[idx];
    }
}

extern "C" void kernel_launch(void* const* d_in, const int* in_sizes, int n_in,
                              void* d_out, int out_size, void* d_ws, size_t ws_size,
                              hipStream_t stream)
{
    const float* x   = (const float*)d_in[0];
    const float* rot = (const float*)d_in[1];
    const float* ent = (const float*)d_in[2];
    float* out = (float*)d_out;

    int T = in_sizes[0] / N_Q;               // 16 * 1024 = 16384
    int grid = (T + ROWS - 1) / ROWS;        // 64 blocks x 4 waves
    hipLaunchKernelGGL(qsa_kernel, dim3(grid), dim3(ROWS), 0, stream,
                       x, rot, ent, out, T);
}